// Round 12
// baseline (186.209 us; speedup 1.0000x reference)
//
#include <hip/hip_runtime.h>

// Shapes (fixed)
#define SEQ   2048
#define NB    2
#define NHQ   32
#define NHKV  8
#define HD    128
#define QTILE 128      // q rows per block (4 waves x 32 q)
#define QW    32
#define KVB   32
#define NT    (SEQ / KVB)    // 64 kv tiles
#define SCALE 0.08838834764831845f
#define QSCALE (0.08838834764831845f * 1.4426950408889634f)   // fold log2(e): use exp2
#define THRL2 11.5f

#define QSTRIDE (NB * NHQ * HD)    // 8192
#define KSTRIDE (NB * NHKV * HD)   // 2048

typedef float f32x2  __attribute__((ext_vector_type(2)));
typedef float f32x4  __attribute__((ext_vector_type(4)));
typedef float f32x8  __attribute__((ext_vector_type(8)));
typedef float f32x16 __attribute__((ext_vector_type(16)));
typedef __bf16 bf16x8 __attribute__((ext_vector_type(8)));
typedef unsigned short ushort8 __attribute__((ext_vector_type(8)));
typedef unsigned int u32;
typedef unsigned int u32x2 __attribute__((ext_vector_type(2)));
typedef unsigned int u32x4 __attribute__((ext_vector_type(4)));

__device__ __forceinline__ unsigned short f2bf(float f) {
    union { float f; unsigned u; } c; c.f = f;
    return (unsigned short)((c.u + 0x7fffu + ((c.u >> 16) & 1u)) >> 16);
}

__device__ __forceinline__ void gload_lds16(const unsigned short* g, unsigned short* l) {
    __builtin_amdgcn_global_load_lds((const __attribute__((address_space(1))) u32*)g,
                                     (__attribute__((address_space(3))) u32*)l, 16, 0, 0);
}

__device__ __forceinline__ float ex2(float x) {
#if __has_builtin(__builtin_amdgcn_exp2f)
    return __builtin_amdgcn_exp2f(x);
#else
    return exp2f(x);
#endif
}

__device__ __forceinline__ u32 cvtpk(float lo, float hi) {
    u32 r;
    asm("v_cvt_pk_bf16_f32 %0, %1, %2" : "=v"(r) : "v"(lo), "v"(hi));
    return r;
}

// v_permlane32_swap_b32 a, b : swaps a's UPPER 32 lanes with b's LOWER 32 lanes
__device__ __forceinline__ void pl32swap(u32& a, u32& b) {
#if __has_builtin(__builtin_amdgcn_permlane32_swap)
    u32x2 r = __builtin_amdgcn_permlane32_swap(a, b, false, false);
    a = r.x; b = r.y;
#else
    asm("v_permlane32_swap_b32 %0, %1" : "+v"(a), "+v"(b));
#endif
}

// Pack 8 f32 P values (C-layout rows r=B..B+7) into one PV B-fragment:
// pa elem j = P[8h + j] of the 16-kv slice. Verified R4.
template <int B>
__device__ __forceinline__ bf16x8 make_pa(const f32x16 p) {
    u32 w0 = cvtpk(p[B + 0], p[B + 1]);
    u32 w2 = cvtpk(p[B + 4], p[B + 5]);
    pl32swap(w0, w2);
    u32 w1 = cvtpk(p[B + 2], p[B + 3]);
    u32 w3 = cvtpk(p[B + 6], p[B + 7]);
    pl32swap(w1, w3);
    u32x4 v = {w0, w1, w2, w3};
    return __builtin_bit_cast(bf16x8, v);
}

__device__ __forceinline__ f32x8 lo8(f32x16 v) {
    return __builtin_shufflevector(v, v, 0, 1, 2, 3, 4, 5, 6, 7);
}
__device__ __forceinline__ f32x8 hi8(f32x16 v) {
    return __builtin_shufflevector(v, v, 8, 9, 10, 11, 12, 13, 14, 15);
}
__device__ __forceinline__ f32x4 lo4(f32x8 v) { return __builtin_shufflevector(v, v, 0, 1, 2, 3); }
__device__ __forceinline__ f32x4 hi4(f32x8 v) { return __builtin_shufflevector(v, v, 4, 5, 6, 7); }

// vector max-reduce of 16 lanes-local floats -> scalar (v_pk_max_f32 pairs)
__device__ __forceinline__ float vmax16(f32x16 v) {
#if __has_builtin(__builtin_elementwise_max)
    f32x8 a = __builtin_elementwise_max(lo8(v), hi8(v));
    f32x4 b = __builtin_elementwise_max(lo4(a), hi4(a));
    float c0 = fmaxf(b[0], b[2]), c1 = fmaxf(b[1], b[3]);
    return fmaxf(c0, c1);
#else
    float m = v[0];
#pragma unroll
    for (int r = 1; r < 16; ++r) m = fmaxf(m, v[r]);
    return m;
#endif
}
// vector sum-reduce -> scalar
__device__ __forceinline__ float vsum16(f32x16 v) {
    f32x8 a = lo8(v) + hi8(v);
    f32x4 b = lo4(a) + hi4(a);
    return (b[0] + b[2]) + (b[1] + b[3]);
}

// ---- pre-pass 1: K -> bf16 fragment-major: Kf[bh][t32][chunk c 0..15][row r 0..31] (16B units)
// unit value j = K[t*32+r][bh][c*8+j]. One block per (bh,t).
__global__ __launch_bounds__(256) void conv_k(const float* __restrict__ K,
                                              unsigned short* __restrict__ Kf) {
    __shared__ float tile[32][129];
    int t  = blockIdx.x & 63;
    int bh = blockIdx.x >> 6;
#pragma unroll
    for (int i = 0; i < 4; ++i) {
        int f4 = i * 256 + threadIdx.x;        // 0..1023 float4s
        int r = f4 >> 5, d4 = (f4 & 31) * 4;
        float4 v = *(const float4*)(K + ((size_t)(t * 32 + r) * 16 + bh) * 128 + d4);
        tile[r][d4] = v.x; tile[r][d4 + 1] = v.y;
        tile[r][d4 + 2] = v.z; tile[r][d4 + 3] = v.w;
    }
    __syncthreads();
#pragma unroll
    for (int i = 0; i < 2; ++i) {
        int lin = i * 256 + threadIdx.x;       // 0..511 = c(16) x r(32)
        int r = lin & 31, c = lin >> 5;
        ushort8 u;
#pragma unroll
        for (int j = 0; j < 8; ++j) u[j] = f2bf(tile[r][c * 8 + j]);
        *(ushort8*)&Kf[((size_t)(bh * 64 + t) * 16 + c) * 256 + r * 8] = u;
    }
}

// ---- pre-pass 2: V -> bf16 fragment-major: Vf[bh][t32][cv 0..3][db 0..3][row r 0..31]
// unit value j = V[t*32 + cv*8 + j][bh][db*32 + r]. One block per (bh,t).
__global__ __launch_bounds__(256) void conv_v(const float* __restrict__ V,
                                              unsigned short* __restrict__ Vf) {
    __shared__ float tile[32][129];
    int t  = blockIdx.x & 63;
    int bh = blockIdx.x >> 6;
#pragma unroll
    for (int i = 0; i < 4; ++i) {
        int f4 = i * 256 + threadIdx.x;
        int kv = f4 >> 5, d4 = (f4 & 31) * 4;
        float4 v = *(const float4*)(V + ((size_t)(t * 32 + kv) * 16 + bh) * 128 + d4);
        tile[kv][d4] = v.x; tile[kv][d4 + 1] = v.y;
        tile[kv][d4 + 2] = v.z; tile[kv][d4 + 3] = v.w;
    }
    __syncthreads();
#pragma unroll
    for (int i = 0; i < 2; ++i) {
        int lin = i * 256 + threadIdx.x;       // 0..511 = cv(4) x db(4) x r(32)
        int r = lin & 31, db = (lin >> 5) & 3, cv = lin >> 7;
        ushort8 u;
#pragma unroll
        for (int j = 0; j < 8; ++j) u[j] = f2bf(tile[cv * 8 + j][db * 32 + r]);
        *(ushort8*)&Vf[((size_t)(bh * 64 + t) * 16 + cv * 4 + db) * 256 + r * 8] = u;
    }
}

// -------- main kernel: 4 waves x 32q, KVB=32; fragment-major LDS double-buffer --------
// buffer i at [i*16384, i*16384+16384): K [0,8192) + V [8192,16384)
// epilogue reuses [0, 34816): 4 waves x 32x68 f32. Total LDS 34816 -> 4 blocks/CU.
__global__ __launch_bounds__(256, 4)
void attn_fwd11(const float* __restrict__ Q, const unsigned short* __restrict__ Kf,
                const unsigned short* __restrict__ Vf, float* __restrict__ O) {
    __shared__ __align__(16) unsigned char smemc[34816];

    const int tid  = threadIdx.x;
    const int w    = tid >> 6;     // 0..3
    const int lane = tid & 63;
    const int q31  = lane & 31;
    const int h    = lane >> 5;

    // XCD-locality decode: hkv = bid&7
    const int bid   = blockIdx.x;
    const int hkv   = bid & 7;
    const int rest  = bid >> 3;
    const int g     = rest & 3;
    const int b     = (rest >> 2) & 1;
    const int qtile = rest >> 3;          // 0..15
    const int hq    = hkv * 4 + g;

    const int qrow = qtile * QTILE + w * QW + q31;

    // ---- Q B-fragments: qf[s] elem j = Q[qrow][16s+8h+j] * QSCALE ----
    bf16x8 qf[8];
    {
        const float* qp = Q + (size_t)qrow * QSTRIDE + b * (NHQ * HD) + hq * HD;
#pragma unroll
        for (int s = 0; s < 8; ++s) {
            const float* p = qp + (2 * s + h) * 8;
            float4 f0 = *(const float4*)(p);
            float4 f1 = *(const float4*)(p + 4);
            ushort8 u;
            u[0] = f2bf(f0.x * QSCALE); u[1] = f2bf(f0.y * QSCALE);
            u[2] = f2bf(f0.z * QSCALE); u[3] = f2bf(f0.w * QSCALE);
            u[4] = f2bf(f1.x * QSCALE); u[5] = f2bf(f1.y * QSCALE);
            u[6] = f2bf(f1.z * QSCALE); u[7] = f2bf(f1.w * QSCALE);
            qf[s] = __builtin_bit_cast(bf16x8, u);
        }
    }

    // fragment-major per-lane bases (stride-1 across lanes => conflict-free)
    const u32 kbase = h * 512 + q31 * 16;                 // + s*1024 + kof
    const u32 vbase = 8192 + h * 2048 + q31 * 16;         // + ks*4096 + db*512 + kof

    f32x16 acc[4];
#pragma unroll
    for (int db = 0; db < 4; ++db) acc[db] = (f32x16)0.f;
    float mr = -3e38f, lsum = 0.f;

    const unsigned short* kbh = Kf + (size_t)(b * 8 + hkv) * 2048 * 128;
    const unsigned short* vbh = Vf + (size_t)(b * 8 + hkv) * 2048 * 128;

    // identity-mapped staging: per wave 2x 1KB for K and V (4 vmem insts)
#define STAGE(sofb, tt) do {                                                           \
        _Pragma("unroll")                                                              \
        for (int i_ = 0; i_ < 2; ++i_) {                                               \
            const int c_ = w * 2 + i_;                                                 \
            gload_lds16(kbh + (size_t)(tt) * 4096 + c_ * 512 + lane * 8,               \
                        (unsigned short*)(smemc + (sofb) + c_ * 1024));                \
            gload_lds16(vbh + (size_t)(tt) * 4096 + c_ * 512 + lane * 8,               \
                        (unsigned short*)(smemc + (sofb) + 8192 + c_ * 1024));         \
        }                                                                              \
    } while (0)

    STAGE(0, 0);
    int kof = 0;        // compute-buffer offset toggles 0 <-> 16384

    for (int t = 0; t < NT; ++t) {
        // own stage loads complete -> barrier -> everyone's tile t is in LDS
        asm volatile("s_waitcnt vmcnt(0)" ::: "memory");
        __builtin_amdgcn_s_barrier();
        if (t + 1 < NT) STAGE(kof ^ 16384, t + 1);

        // ---- QK(t): S^T = K * Q ----
        f32x16 sa = (f32x16)0.f;
        __builtin_amdgcn_s_setprio(1);
#pragma unroll
        for (int s = 0; s < 8; ++s) {
            bf16x8 kf = *(const bf16x8*)&smemc[kbase + s * 1024 + kof];
            sa = __builtin_amdgcn_mfma_f32_32x32x16_bf16(kf, qf[s], sa, 0, 0, 0);
        }
        __builtin_amdgcn_s_setprio(0);

        // ---- in-register online softmax (log2 domain, packed-f32 VALU) ----
        {
            float tm = vmax16(sa);
            tm = fmaxf(tm, __shfl_xor(tm, 32));
            if (!__all(tm <= mr + THRL2)) {           // defer-max (T13)
                float mn   = fmaxf(mr, tm);
                float corr = ex2(mr - mn);
                lsum *= corr;
#pragma unroll
                for (int db = 0; db < 4; ++db) acc[db] = acc[db] * corr;
                mr = mn;
            }
            sa = sa - mr;                              // v_pk_add x8
#pragma unroll
            for (int r = 0; r < 16; ++r) sa[r] = ex2(sa[r]);
            lsum += vsum16(sa);                        // cross-h shfl deferred to epilogue
        }

        // ---- P -> bf16 PV fragments ----
        bf16x8 pa[2];
        pa[0] = make_pa<0>(sa);
        pa[1] = make_pa<8>(sa);

        // ---- PV(t): O^T += V^T * P^T ----
        __builtin_amdgcn_s_setprio(1);
#pragma unroll
        for (int db = 0; db < 4; ++db) {
#pragma unroll
            for (int ks = 0; ks < 2; ++ks) {
                bf16x8 vf = *(const bf16x8*)&smemc[vbase + ks * 4096 + db * 512 + kof];
                acc[db] = __builtin_amdgcn_mfma_f32_32x32x16_bf16(vf, pa[ks], acc[db], 0, 0, 0);
            }
        }
        __builtin_amdgcn_s_setprio(0);

        kof ^= 16384;
    }
#undef STAGE

    // ---- epilogue: final lsum reduce, normalize, LDS transpose, coalesced stores ----
    __syncthreads();   // all waves done reading K/V LDS
    lsum += __shfl_xor(lsum, 32);
    float invl = 1.f / lsum;
    float* ep = (float*)(void*)smemc + w * 2176;   // 32 x 68 f32 per wave
    const int qtb = qtile * QTILE + w * QW;
    float* ob = O + b * (NHQ * HD) + hq * HD;

#pragma unroll
    for (int pass = 0; pass < 2; ++pass) {
#pragma unroll
        for (int db2 = 0; db2 < 2; ++db2) {
            const int db = pass * 2 + db2;
#pragma unroll
            for (int r = 0; r < 16; ++r)
                ep[q31 * 68 + db2 * 32 + (r & 3) + 8 * (r >> 2) + 4 * h] = acc[db][r] * invl;
        }
        __syncthreads();
#pragma unroll
        for (int i = 0; i < 8; ++i) {
            const int row = i * 4 + (lane >> 4);
            const int f4  = lane & 15;
            float4 val = *(const float4*)&ep[row * 68 + f4 * 4];
            *(float4*)(ob + (size_t)(qtb + row) * QSTRIDE + pass * 64 + f4 * 4) = val;
        }
        __syncthreads();
    }
}

// ---------------- fallback (round-1 kernel, used if ws too small) ----------------
#define KPAD  136
#define VPAD  72
#define PPAD  72
__global__ __launch_bounds__(512, 2)
void attn_fwd(const float* __restrict__ Q, const float* __restrict__ K,
              const float* __restrict__ V, float* __restrict__ O) {
    __shared__ __align__(16) unsigned short kbuf[64 * KPAD];
    __shared__ __align__(16) unsigned short vbuf[HD * VPAD];
    __shared__ __align__(16) unsigned short pbuf[8][16 * PPAD];

    const int tid = threadIdx.x;
    const int w = tid >> 6, lane = tid & 63;
    const int row16 = lane & 15, kg = lane >> 4;
    const int bid = blockIdx.x;
    const int qtile = bid & 7, g = (bid >> 3) & 3, b = (bid >> 5) & 1, hkv = bid >> 6;
    const int hq = hkv * 4 + g;
    const int qbase = qtile * 256 + w * 32;

    ushort8 qf[2][4];
#pragma unroll
    for (int s = 0; s < 2; ++s) {
        const int qrow = qbase + s * 16 + row16;
        const float* qp = Q + (size_t)qrow * QSTRIDE + b * (NHQ * HD) + hq * HD;
#pragma unroll
        for (int kk = 0; kk < 4; ++kk) {
            const float* p = qp + kk * 32 + kg * 8;
            float4 f0 = *(const float4*)(p);
            float4 f1 = *(const float4*)(p + 4);
            ushort8 u;
            u[0] = f2bf(f0.x * SCALE); u[1] = f2bf(f0.y * SCALE);
            u[2] = f2bf(f0.z * SCALE); u[3] = f2bf(f0.w * SCALE);
            u[4] = f2bf(f1.x * SCALE); u[5] = f2bf(f1.y * SCALE);
            u[6] = f2bf(f1.z * SCALE); u[7] = f2bf(f1.w * SCALE);
            qf[s][kk] = u;
        }
    }
    float m[2][4], lsum[2][4];
    f32x4 acco[2][8];
#pragma unroll
    for (int s = 0; s < 2; ++s)
#pragma unroll
        for (int r = 0; r < 4; ++r) { m[s][r] = -1e30f; lsum[s][r] = 0.f; }
#pragma unroll
    for (int s = 0; s < 2; ++s)
#pragma unroll
        for (int n = 0; n < 8; ++n) acco[s][n] = (f32x4)0.f;

    const float* kb0 = K + b * (NHKV * HD) + hkv * HD;
    const float* vb0 = V + b * (NHKV * HD) + hkv * HD;

    for (int kvt = 0; kvt < SEQ / 64; ++kvt) {
        const int kv0 = kvt * 64;
        __syncthreads();
        const float* kb = kb0 + (size_t)kv0 * KSTRIDE;
#pragma unroll
        for (int i = 0; i < 2; ++i) {
            int c = i * 512 + tid;
            int row = c >> 4, c8 = c & 15;
            const float* src = kb + (size_t)row * KSTRIDE + c8 * 8;
            float4 f0 = *(const float4*)(src);
            float4 f1 = *(const float4*)(src + 4);
            ushort8 u;
            u[0] = f2bf(f0.x); u[1] = f2bf(f0.y); u[2] = f2bf(f0.z); u[3] = f2bf(f0.w);
            u[4] = f2bf(f1.x); u[5] = f2bf(f1.y); u[6] = f2bf(f1.z); u[7] = f2bf(f1.w);
            *(ushort8*)&kbuf[row * KPAD + c8 * 8] = u;
        }
        const float* vb = vb0 + (size_t)kv0 * KSTRIDE;
#pragma unroll
        for (int i = 0; i < 4; ++i) {
            int f4i = i * 512 + tid;
            int kv = f4i >> 5, d0 = (f4i & 31) * 4;
            float4 v4 = *(const float4*)(vb + (size_t)kv * KSTRIDE + d0);
            vbuf[(d0 + 0) * VPAD + kv] = f2bf(v4.x);
            vbuf[(d0 + 1) * VPAD + kv] = f2bf(v4.y);
            vbuf[(d0 + 2) * VPAD + kv] = f2bf(v4.z);
            vbuf[(d0 + 3) * VPAD + kv] = f2bf(v4.w);
        }
        __syncthreads();

        f32x4 sa[2][4];
#pragma unroll
        for (int s = 0; s < 2; ++s)
#pragma unroll
            for (int n = 0; n < 4; ++n) sa[s][n] = (f32x4)0.f;
#pragma unroll
        for (int kk = 0; kk < 4; ++kk) {
#pragma unroll
            for (int n = 0; n < 4; ++n) {
                bf16x8 bfr = *(const bf16x8*)&kbuf[(n * 16 + row16) * KPAD + kk * 32 + kg * 8];
                sa[0][n] = __builtin_amdgcn_mfma_f32_16x16x32_bf16(
                    __builtin_bit_cast(bf16x8, qf[0][kk]), bfr, sa[0][n], 0, 0, 0);
                sa[1][n] = __builtin_amdgcn_mfma_f32_16x16x32_bf16(
                    __builtin_bit_cast(bf16x8, qf[1][kk]), bfr, sa[1][n], 0, 0, 0);
            }
        }
#pragma unroll
        for (int s = 0; s < 2; ++s) {
#pragma unroll
            for (int r = 0; r < 4; ++r) {
                float tm = fmaxf(fmaxf(sa[s][0][r], sa[s][1][r]), fmaxf(sa[s][2][r], sa[s][3][r]));
                tm = fmaxf(tm, __shfl_xor(tm, 1, 16));
                tm = fmaxf(tm, __shfl_xor(tm, 2, 16));
                tm = fmaxf(tm, __shfl_xor(tm, 4, 16));
                tm = fmaxf(tm, __shfl_xor(tm, 8, 16));
                float mn = fmaxf(m[s][r], tm);
                float corr = __expf(m[s][r] - mn);
                float ps = 0.f;
                int prow = kg * 4 + r;
#pragma unroll
                for (int n = 0; n < 4; ++n) {
                    float p = __expf(sa[s][n][r] - mn);
                    ps += p;
                    pbuf[w][prow * PPAD + n * 16 + row16] = f2bf(p);
                }
                ps += __shfl_xor(ps, 1, 16);
                ps += __shfl_xor(ps, 2, 16);
                ps += __shfl_xor(ps, 4, 16);
                ps += __shfl_xor(ps, 8, 16);
                lsum[s][r] = lsum[s][r] * corr + ps;
                m[s][r] = mn;
#pragma unroll
                for (int n8 = 0; n8 < 8; ++n8) acco[s][n8][r] *= corr;
            }
#pragma unroll
            for (int kk2 = 0; kk2 < 2; ++kk2) {
                bf16x8 pa = *(const bf16x8*)&pbuf[w][row16 * PPAD + kk2 * 32 + kg * 8];
#pragma unroll
                for (int n8 = 0; n8 < 8; ++n8) {
                    bf16x8 vf = *(const bf16x8*)&vbuf[(n8 * 16 + row16) * VPAD + kk2 * 32 + kg * 8];
                    acco[s][n8] = __builtin_amdgcn_mfma_f32_16x16x32_bf16(pa, vf, acco[s][n8], 0, 0, 0);
                }
            }
        }
    }
    float* ob = O + b * (NHQ * HD) + hq * HD;
#pragma unroll
    for (int s = 0; s < 2; ++s)
#pragma unroll
        for (int r = 0; r < 4; ++r) {
            float inv = 1.f / lsum[s][r];
            int qrow = qbase + s * 16 + kg * 4 + r;
            float* op = ob + (size_t)qrow * QSTRIDE;
#pragma unroll
            for (int n8 = 0; n8 < 8; ++n8)
                op[n8 * 16 + row16] = acco[s][n8][r] * inv;
        }
}

extern "C" void kernel_launch(void* const* d_in, const int* in_sizes, int n_in,
                              void* d_out, int out_size, void* d_ws, size_t ws_size,
                              hipStream_t stream) {
    (void)in_sizes; (void)n_in; (void)out_size;
    const float* Q = (const float*)d_in[0];
    const float* K = (const float*)d_in[1];
    const float* V = (const float*)d_in[2];
    float* Out = (float*)d_out;

    const size_t kv_elems = (size_t)16 * 2048 * 128;
    const size_t need = kv_elems * 2 * sizeof(unsigned short);

    if (ws_size >= need) {
        unsigned short* Kf = (unsigned short*)d_ws;
        unsigned short* Vf = Kf + kv_elems;
        conv_k<<<dim3(1024), dim3(256), 0, stream>>>(K, Kf);
        conv_v<<<dim3(1024), dim3(256), 0, stream>>>(V, Vf);
        attn_fwd11<<<dim3(1024), dim3(256), 0, stream>>>(Q, Kf, Vf, Out);
    } else {
        attn_fwd<<<dim3(512), dim3(512), 0, stream>>>(Q, K, V, Out);
    }
}